// Round 3
// baseline (487.141 us; speedup 1.0000x reference)
//
#include <hip/hip_runtime.h>

// ROI max pooling, matching the JAX reference:
//   img:  (1, 200, 200, 512) fp32, NHWC
//   rois: (1, 128, 4) fp32 as (x, y, w, h) in feature-map pixels
//   pool: 7  ->  out: (1, 128, 7, 7, 512) fp32
//
// Bin boundaries replicate  int(x + k*(w/P))  in strict IEEE fp32
// (separate div/mul/add, no FMA contraction) -> bit-exact pixel sets.
//
// R3: persistent waves + atomic work queue (kills drain tail / imbalance),
// task = (roi, bin, channel-quarter) -> 25088 fine-grained tasks,
// clamp-padded loops (max is idempotent, duplicate loads harmless) for
// branch-free deep MLP. One wave per task: lane>>5 = pixel parity,
// lane&31 = float4 slot within the 128-channel quarter.

#define IMG_H 200
#define IMG_W 200
#define IMG_C 512
#define C4 (IMG_C / 4)          // 128 float4 per pixel
#define POOL 7
#define NROI 128
#define NTASK (NROI * POOL * POOL * 4)   // 25088

__device__ __forceinline__ float4 max4(float4 a, float4 b) {
    return make_float4(fmaxf(a.x, b.x), fmaxf(a.y, b.y),
                       fmaxf(a.z, b.z), fmaxf(a.w, b.w));
}

__global__ __launch_bounds__(256) void roi_pool_persistent(
    const float* __restrict__ img,
    const float* __restrict__ rois,
    float* __restrict__ out,
    unsigned int* __restrict__ queue)
{
    const int lane = threadIdx.x & 63;
    const int p    = lane >> 5;        // pixel parity within a wave
    const int c    = lane & 31;        // float4 index within 128-ch quarter

    const float4* __restrict__ img4 = (const float4*)img;
    float4* __restrict__ out4 = (float4*)out;

    for (;;) {
        unsigned int task;
        if (lane == 0) task = atomicAdd(queue, 1u);
        task = (unsigned int)__shfl((int)task, 0, 64);
        if (task >= NTASK) break;

        const int quarter = task & 3;          // innermost: 4 waves share pixels
        const int binroi  = task >> 2;
        const int bin = binroi % (POOL * POOL);
        const int roi = binroi / (POOL * POOL);
        const int jy = bin / POOL;
        const int ix = bin % POOL;

        const float rx = rois[roi * 4 + 0];
        const float ry = rois[roi * 4 + 1];
        const float rw = rois[roi * 4 + 2];
        const float rh = rois[roi * 4 + 3];

        // Strict fp32, no contraction: s = w/P; b[k] = int(x + k*s)
        const float sx = __fdiv_rn(rw, 7.0f);
        const float sy = __fdiv_rn(rh, 7.0f);
        const int x1 = (int)__fadd_rn(rx, __fmul_rn((float)ix,       sx));
        const int x2 = (int)__fadd_rn(rx, __fmul_rn((float)(ix + 1), sx));
        const int y1 = (int)__fadd_rn(ry, __fmul_rn((float)jy,       sy));
        const int y2 = (int)__fadd_rn(ry, __fmul_rn((float)(jy + 1), sy));

        const int x2m1 = x2 - 1;
        const int y2m1 = y2 - 1;
        const int nx  = (x2 - x1 + 1) >> 1;    // parity covers 2 cols per step
        const int nyp = (y2 - y1 + 1) >> 1;    // row pairs (clamped)

        const float4* __restrict__ img4q = img4 + quarter * 32 + c;

        float4 m0 = make_float4(-INFINITY, -INFINITY, -INFINITY, -INFINITY);
        float4 m1 = m0;

        for (int r = 0; r < nyp; ++r) {
            const int yA = y1 + 2 * r;
            const int yB = min(yA + 1, y2m1);
            const float4* __restrict__ rowA = img4q + (size_t)yA * (IMG_W * C4);
            const float4* __restrict__ rowB = img4q + (size_t)yB * (IMG_W * C4);
            #pragma unroll 2
            for (int k = 0; k < nx; ++k) {
                int xx = x1 + 2 * k + p;
                xx = min(xx, x2m1);
                const size_t o = (size_t)xx * C4;
                m0 = max4(m0, rowA[o]);
                m1 = max4(m1, rowB[o]);
            }
        }
        m0 = max4(m0, m1);

        // cross-parity reduce (lane ^ 32)
        float4 res;
        res.x = fmaxf(m0.x, __shfl_xor(m0.x, 32, 64));
        res.y = fmaxf(m0.y, __shfl_xor(m0.y, 32, 64));
        res.z = fmaxf(m0.z, __shfl_xor(m0.z, 32, 64));
        res.w = fmaxf(m0.w, __shfl_xor(m0.w, 32, 64));

        if (p == 0) {
            out4[(size_t)((roi * (POOL * POOL) + bin) * C4) + quarter * 32 + c] = res;
        }
    }
}

extern "C" void kernel_launch(void* const* d_in, const int* in_sizes, int n_in,
                              void* d_out, int out_size, void* d_ws, size_t ws_size,
                              hipStream_t stream) {
    (void)in_sizes; (void)n_in; (void)ws_size; (void)out_size;
    const float* img  = (const float*)d_in[0];
    const float* rois = (const float*)d_in[1];
    float* out = (float*)d_out;
    unsigned int* queue = (unsigned int*)d_ws;

    hipMemsetAsync(queue, 0, sizeof(unsigned int), stream);

    // 8 blocks/CU target; extra blocks just find the queue empty and exit.
    dim3 grid(2048);
    dim3 block(256);
    roi_pool_persistent<<<grid, block, 0, stream>>>(img, rois, out, queue);
}

// Round 4
// 147.773 us; speedup vs baseline: 3.2966x; 3.2966x over previous
//
#include <hip/hip_runtime.h>

// ROI max pooling, matching the JAX reference:
//   img:  (1, 200, 200, 512) fp32, NHWC
//   rois: (1, 128, 4) fp32 as (x, y, w, h) in feature-map pixels
//   pool: 7  ->  out: (1, 128, 7, 7, 512) fp32
//
// Bin boundaries replicate  int(x + k*(w/P))  in strict IEEE fp32
// (separate div/mul/add, no FMA contraction) -> bit-exact pixel sets.
//
// R4: back to fixed one-block-per-(roi,bin) mapping (R3's atomic queue
// serialized at ~15ns/op). Fixes vs R2:
//  - explicit 8-load batch (4 rows x 2 cols, clamp-padded; max is
//    idempotent so duplicate clamped loads are harmless) with 8 independent
//    accumulator chains -> guaranteed MLP=8 (R2's VGPR=36 proved MLP~4)
//  - __launch_bounds__(128,4) so the register allocator may use ~128 VGPRs
//  - XCD swizzle: all 49 bins of a ROI on one XCD (b&7) for L2 locality

#define IMG_H 200
#define IMG_W 200
#define IMG_C 512
#define C4 (IMG_C / 4)          // 128 float4 per pixel
#define POOL 7
#define NROI 128

__device__ __forceinline__ float4 max4(float4 a, float4 b) {
    return make_float4(fmaxf(a.x, b.x), fmaxf(a.y, b.y),
                       fmaxf(a.z, b.z), fmaxf(a.w, b.w));
}

__global__ __launch_bounds__(128, 4) void roi_pool_kernel(
    const float* __restrict__ img,
    const float* __restrict__ rois,
    float* __restrict__ out)
{
    // XCD-aware swizzle: blocks with the same (b & 7) are claimed to land on
    // the same XCD; give each XCD 16 whole ROIs (16*49 = 784 blocks each).
    const int b     = blockIdx.x;
    const int xcd   = b & 7;
    const int local = b >> 3;            // 0..783
    const int roi   = xcd * (NROI / 8) + local / (POOL * POOL);
    const int bin   = local % (POOL * POOL);
    const int jy = bin / POOL;
    const int ix = bin % POOL;

    const float rx = rois[roi * 4 + 0];
    const float ry = rois[roi * 4 + 1];
    const float rw = rois[roi * 4 + 2];
    const float rh = rois[roi * 4 + 3];

    // Strict fp32, no contraction: s = w/P; b[k] = int(x + k*s)
    const float sx = __fdiv_rn(rw, 7.0f);
    const float sy = __fdiv_rn(rh, 7.0f);
    const int x1 = (int)__fadd_rn(rx, __fmul_rn((float)ix,       sx));
    const int x2 = (int)__fadd_rn(rx, __fmul_rn((float)(ix + 1), sx));
    const int y1 = (int)__fadd_rn(ry, __fmul_rn((float)jy,       sy));
    const int y2 = (int)__fadd_rn(ry, __fmul_rn((float)(jy + 1), sy));

    const int x2m1 = x2 - 1;
    const int y2m1 = y2 - 1;
    const int nr = (y2 - y1 + 3) >> 2;   // row quads (clamped)
    const int nc = (x2 - x1 + 1) >> 1;   // col pairs (clamped)

    const int c4 = threadIdx.x;          // 0..127, one float4 of channels
    const float4* __restrict__ img4 = (const float4*)img + c4;

    float4 ninf = make_float4(-INFINITY, -INFINITY, -INFINITY, -INFINITY);
    float4 m0 = ninf, m1 = ninf, m2 = ninf, m3 = ninf;
    float4 m4 = ninf, m5 = ninf, m6 = ninf, m7 = ninf;

    for (int r = 0; r < nr; ++r) {
        const int yb = y1 + 4 * r;
        const int ya0 = min(yb,     y2m1);
        const int ya1 = min(yb + 1, y2m1);
        const int ya2 = min(yb + 2, y2m1);
        const int ya3 = min(yb + 3, y2m1);
        const float4* __restrict__ p0 = img4 + (size_t)ya0 * (IMG_W * C4);
        const float4* __restrict__ p1 = img4 + (size_t)ya1 * (IMG_W * C4);
        const float4* __restrict__ p2 = img4 + (size_t)ya2 * (IMG_W * C4);
        const float4* __restrict__ p3 = img4 + (size_t)ya3 * (IMG_W * C4);
        for (int k = 0; k < nc; ++k) {
            const int xa = min(x1 + 2 * k,     x2m1);
            const int xb = min(x1 + 2 * k + 1, x2m1);
            const size_t oa = (size_t)xa * C4;
            const size_t ob = (size_t)xb * C4;
            // 8 independent loads in flight, 8 independent max chains.
            float4 v0 = p0[oa];
            float4 v1 = p0[ob];
            float4 v2 = p1[oa];
            float4 v3 = p1[ob];
            float4 v4 = p2[oa];
            float4 v5 = p2[ob];
            float4 v6 = p3[oa];
            float4 v7 = p3[ob];
            m0 = max4(m0, v0);
            m1 = max4(m1, v1);
            m2 = max4(m2, v2);
            m3 = max4(m3, v3);
            m4 = max4(m4, v4);
            m5 = max4(m5, v5);
            m6 = max4(m6, v6);
            m7 = max4(m7, v7);
        }
    }
    m0 = max4(m0, m1);
    m2 = max4(m2, m3);
    m4 = max4(m4, m5);
    m6 = max4(m6, m7);
    m0 = max4(m0, m2);
    m4 = max4(m4, m6);
    m0 = max4(m0, m4);

    float4* __restrict__ out4 = (float4*)out;
    out4[((size_t)(roi * (POOL * POOL) + bin)) * C4 + c4] = m0;
}

extern "C" void kernel_launch(void* const* d_in, const int* in_sizes, int n_in,
                              void* d_out, int out_size, void* d_ws, size_t ws_size,
                              hipStream_t stream) {
    (void)in_sizes; (void)n_in; (void)d_ws; (void)ws_size; (void)out_size;
    const float* img  = (const float*)d_in[0];
    const float* rois = (const float*)d_in[1];
    float* out = (float*)d_out;

    dim3 grid(NROI * POOL * POOL);
    dim3 block(128);
    roi_pool_kernel<<<grid, block, 0, stream>>>(img, rois, out);
}

// Round 5
// 142.885 us; speedup vs baseline: 3.4093x; 1.0342x over previous
//
#include <hip/hip_runtime.h>

// ROI max pooling, matching the JAX reference:
//   img:  (1, 200, 200, 512) fp32, NHWC
//   rois: (1, 128, 4) fp32 as (x, y, w, h) in feature-map pixels
//   pool: 7  ->  out: (1, 128, 7, 7, 512) fp32
//
// Bin boundaries replicate  int(x + k*(w/P))  in strict IEEE fp32
// (separate div/mul/add, no FMA contraction) -> bit-exact pixel sets.
//
// R5: explicit software pipeline. R4's VGPR=44 proved the compiler
// collapsed the 8-load batch to MLP~2-3 (load->max interleave, register
// reuse) -> stuck at ~3 TB/s fill. Here batch i+1's 8 loads are issued
// into a separate register set BEFORE batch i is consumed, pinned by
// sched_barrier(0); tail is clamp-padded (max idempotent) so the loop
// body is branch-free and every iteration issues 8 fresh loads.

#define IMG_H 200
#define IMG_W 200
#define IMG_C 512
#define C4 (IMG_C / 4)          // 128 float4 per pixel
#define ROWSTRIDE ((size_t)IMG_W * C4)
#define POOL 7
#define NROI 128

__device__ __forceinline__ float4 max4(float4 a, float4 b) {
    return make_float4(fmaxf(a.x, b.x), fmaxf(a.y, b.y),
                       fmaxf(a.z, b.z), fmaxf(a.w, b.w));
}

__global__ __launch_bounds__(128, 2) void roi_pool_kernel(
    const float* __restrict__ img,
    const float* __restrict__ rois,
    float* __restrict__ out)
{
    const int bin = blockIdx.x % (POOL * POOL);
    const int roi = blockIdx.x / (POOL * POOL);
    const int jy = bin / POOL;
    const int ix = bin % POOL;

    const float rx = rois[roi * 4 + 0];
    const float ry = rois[roi * 4 + 1];
    const float rw = rois[roi * 4 + 2];
    const float rh = rois[roi * 4 + 3];

    // Strict fp32, no contraction: s = w/P; b[k] = int(x + k*s)
    const float sx = __fdiv_rn(rw, 7.0f);
    const float sy = __fdiv_rn(rh, 7.0f);
    const int x1 = (int)__fadd_rn(rx, __fmul_rn((float)ix,       sx));
    const int x2 = (int)__fadd_rn(rx, __fmul_rn((float)(ix + 1), sx));
    const int y1 = (int)__fadd_rn(ry, __fmul_rn((float)jy,       sy));
    const int y2 = (int)__fadd_rn(ry, __fmul_rn((float)(jy + 1), sy));

    const int x2m1 = x2 - 1;
    const int y2m1 = y2 - 1;
    const int nc  = (x2 - x1 + 1) >> 1;   // col pairs (clamped)
    const int nrq = (y2 - y1 + 3) >> 2;   // row quads (clamped)
    const int nIter = nc * nrq;

    const int c4 = threadIdx.x;           // 0..127, one float4 of channels
    const float4* __restrict__ img4 = (const float4*)img + c4;

    // 8 pixels at (row-quad r, col-pair k), clamp-padded.
    auto load8 = [&](int r, int k,
                     float4& a0, float4& a1, float4& a2, float4& a3,
                     float4& a4, float4& a5, float4& a6, float4& a7) {
        const int yb = y1 + 4 * r;
        const int yA = min(yb,     y2m1);
        const int yB = min(yb + 1, y2m1);
        const int yC = min(yb + 2, y2m1);
        const int yD = min(yb + 3, y2m1);
        const int xa = min(x1 + 2 * k,     x2m1);
        const int xb = min(x1 + 2 * k + 1, x2m1);
        const size_t oa = (size_t)xa * C4;
        const size_t ob = (size_t)xb * C4;
        const float4* pA = img4 + (size_t)yA * ROWSTRIDE;
        const float4* pB = img4 + (size_t)yB * ROWSTRIDE;
        const float4* pC = img4 + (size_t)yC * ROWSTRIDE;
        const float4* pD = img4 + (size_t)yD * ROWSTRIDE;
        a0 = pA[oa]; a1 = pA[ob];
        a2 = pB[oa]; a3 = pB[ob];
        a4 = pC[oa]; a5 = pC[ob];
        a6 = pD[oa]; a7 = pD[ob];
    };

    float4 ninf = make_float4(-INFINITY, -INFINITY, -INFINITY, -INFINITY);
    float4 acc0 = ninf, acc1 = ninf, acc2 = ninf, acc3 = ninf;

    float4 A0, A1, A2, A3, A4, A5, A6, A7;
    float4 B0, B1, B2, B3, B4, B5, B6, B7;

    load8(0, 0, A0, A1, A2, A3, A4, A5, A6, A7);

    int r = 0, k = 0;
    for (int i = 0; i < nIter; ++i) {
        // next coordinates (wave-uniform; clamp at the tail -> re-load same
        // pixels, harmless for max)
        int k2 = k + 1, r2 = r;
        if (k2 == nc) { k2 = 0; r2 = r + 1; }
        const bool last = (i + 1 >= nIter);
        const int rn = last ? r : r2;
        const int kn = last ? k : k2;

        load8(rn, kn, B0, B1, B2, B3, B4, B5, B6, B7);

        // Pin: all 8 prefetch loads are issued before the consuming maxes.
        __builtin_amdgcn_sched_barrier(0);

        acc0 = max4(acc0, max4(A0, A1));
        acc1 = max4(acc1, max4(A2, A3));
        acc2 = max4(acc2, max4(A4, A5));
        acc3 = max4(acc3, max4(A6, A7));

        A0 = B0; A1 = B1; A2 = B2; A3 = B3;
        A4 = B4; A5 = B5; A6 = B6; A7 = B7;
        k = k2; r = r2;
    }

    acc0 = max4(acc0, acc1);
    acc2 = max4(acc2, acc3);
    acc0 = max4(acc0, acc2);

    float4* __restrict__ out4 = (float4*)out;
    out4[((size_t)(roi * (POOL * POOL) + bin)) * C4 + c4] = acc0;
}

extern "C" void kernel_launch(void* const* d_in, const int* in_sizes, int n_in,
                              void* d_out, int out_size, void* d_ws, size_t ws_size,
                              hipStream_t stream) {
    (void)in_sizes; (void)n_in; (void)d_ws; (void)ws_size; (void)out_size;
    const float* img  = (const float*)d_in[0];
    const float* rois = (const float*)d_in[1];
    float* out = (float*)d_out;

    dim3 grid(NROI * POOL * POOL);
    dim3 block(128);
    roi_pool_kernel<<<grid, block, 0, stream>>>(img, rois, out);
}